// Round 4
// baseline (248.600 us; speedup 1.0000x reference)
//
#include <hip/hip_runtime.h>

// EdgeConv fused pipeline, MI355X gfx950 — round 12.
// R11 post-mortem: structural collapse landed (pass2 84->70us, LDS 5KB,
// conflicts 0, absmax unchanged) but total rose 219->237: stats1's edge
// gather costs what old pass1 did. Arithmetic: per-edge VALU ~= 5-15us
// chip-wide, gather BW ~= 16us -- yet each edge-pass runs 70-90us at
// Occupancy 38%. Diagnosis: gather-LATENCY-bound, capped at 16 waves/CU by
// the (256,4) launch bound (VGPR=64/SGPR=32/LDS=5KB would allow 32 waves).
// R12 single change: DROP the min-waves arg on k_stats1/k_pass2. Relaxing
// the cap is allocator-safe (both spill disasters came from tightening);
// HW schedules residency from actual usage -> up to 8 blocks/CU.
// Tripwire: VGPR>128 or FETCH/WRITE blowup = spill -> revert.

#define N_NODES 100000
#define KE 16
#define E_EDGES (N_NODES * KE)
#define BN_EPS 1e-5f
#define NCHUNK (N_NODES / KE)      // 6250 16-node block-chunks (exact)
#define NTILES (N_NODES / 16)      // 6250 16-node GEMM tiles (exact)
#define GSLOTS 16

typedef __attribute__((ext_vector_type(8))) short bf16x8;  // 8 bf16 (4 VGPRs)
typedef __attribute__((ext_vector_type(4))) float f32x4;   // MFMA C/D
typedef __attribute__((ext_vector_type(4))) int i32x4;

#define MFMA(a, b, c) __builtin_amdgcn_mfma_f32_16x16x32_bf16((a), (b), (c), 0, 0, 0)

static __device__ __forceinline__ short bf16b(float f) {
  __bf16 h = (__bf16)f;  // RNE, hardware cvt on gfx950
  return __builtin_bit_cast(short, h);
}

#if __has_builtin(__builtin_amdgcn_cvt_pk_bf16_f32)
static __device__ __forceinline__ int pk2(float a, float b) {
  return __builtin_bit_cast(int, __builtin_amdgcn_cvt_pk_bf16_f32(a, b));
}
#else
static __device__ __forceinline__ int pk2(float a, float b) {
  return (int)(unsigned short)bf16b(a) | ((int)(unsigned short)bf16b(b) << 16);
}
#endif

static __device__ __forceinline__ bf16x8 pack8(float4 a, float4 b) {
  i32x4 v = {pk2(a.x, a.y), pk2(a.z, a.w), pk2(b.x, b.y), pk2(b.z, b.w)};
  return __builtin_bit_cast(bf16x8, v);
}

static __device__ __forceinline__ bf16x8 pack8f(const float h[8]) {
  i32x4 v = {pk2(h[0], h[1]), pk2(h[2], h[3]), pk2(h[4], h[5]), pk2(h[6], h[7])};
  return __builtin_bit_cast(bf16x8, v);
}

static __device__ __forceinline__ float bf2f(short s) {
  unsigned u = ((unsigned)(unsigned short)s) << 16;
  return __builtin_bit_cast(float, u);
}

// ---- prep: weight packing + gacc zeroing -----------------------------------
// wp1[(s*4+t)*64 + l] holds 8 bf16: B[k=32s + (l>>4)*8 + j][c=16t + (l&15)]
// s=0,1 -> Wd = W1[:64]-W1[64:] (xi part); s=2,3 -> Wb = W1[64:] (xj part).
__global__ __launch_bounds__(256) void k_prep(const float* __restrict__ W1,
                                              const float* __restrict__ W2,
                                              short* __restrict__ wp1,
                                              short* __restrict__ wp2,
                                              float* __restrict__ gaccz) {
  if (blockIdx.x == 6) {  // zero both gacc buffers (4096 floats)
    float4 z = {0.f, 0.f, 0.f, 0.f};
    for (int i = 0; i < 4; i++)
      ((float4*)gaccz)[threadIdx.x * 4 + i] = z;
    return;
  }
  int tid = blockIdx.x * 256 + threadIdx.x;
  if (tid < 1024) {
    int l = tid & 63, st = tid >> 6;
    int s = st >> 2, t = st & 3;
    int quad = l >> 4, n16 = l & 15;
    for (int j = 0; j < 8; j++) {
      int k = 32 * s + quad * 8 + j, c = 16 * t + n16;
      float w = (s < 2) ? (W1[k * 64 + c] - W1[(k + 64) * 64 + c])
                        : W1[k * 64 + c];
      wp1[tid * 8 + j] = bf16b(w);
    }
  } else if (tid < 1536) {
    int e = tid - 1024;
    int l = e & 63, st = e >> 6;
    int s = st >> 2, t = st & 3;
    int quad = l >> 4, n16 = l & 15;
    for (int j = 0; j < 8; j++) {
      int k = 32 * s + quad * 8 + j, c = 16 * t + n16;
      wp2[e * 8 + j] = bf16b(W2[k * 64 + c]);
    }
  }
}

// ---- node GEMMs: Y = X@Wd (f32), Z = X@Wb (bf16) ---------------------------
// One 16-node tile per wave; A-frags packed on the fly from f32 x.
__global__ __launch_bounds__(256) void k_nodeYZ(const float* __restrict__ x,
                                                const bf16x8* __restrict__ wp1,
                                                float* __restrict__ Yf,
                                                short* __restrict__ Z) {
  int wave = threadIdx.x >> 6, l = threadIdx.x & 63, quad = l >> 4, n16 = l & 15;
  int tile = blockIdx.x * 4 + wave;
  if (tile >= NTILES) return;
  const float* xr = x + (size_t)(tile * 16 + n16) * 64 + quad * 8;
  float4 x0 = *(const float4*)xr, x1 = *(const float4*)(xr + 4);
  float4 x2 = *(const float4*)(xr + 32), x3 = *(const float4*)(xr + 36);
  bf16x8 a0 = pack8(x0, x1);   // A[m=n16][k = quad*8+j]       (ch 0..31)
  bf16x8 a1 = pack8(x2, x3);   // A[m=n16][k = 32+quad*8+j]    (ch 32..63)
  f32x4 zero = {0.f, 0.f, 0.f, 0.f};
#pragma unroll
  for (int t = 0; t < 4; t++) {
    f32x4 y = MFMA(a0, wp1[(0 + t) * 64 + l], zero);
    y = MFMA(a1, wp1[(4 + t) * 64 + l], y);
    f32x4 z = MFMA(a0, wp1[(8 + t) * 64 + l], zero);
    z = MFMA(a1, wp1[(12 + t) * 64 + l], z);
#pragma unroll
    for (int r = 0; r < 4; r++) {  // D: row = quad*4+r, col = 16t+n16
      size_t row = (size_t)(tile * 16 + quad * 4 + r);
      Yf[row * 64 + 16 * t + n16] = y[r];
      Z[row * 64 + 16 * t + n16] = bf16b(z[r]);
    }
  }
}

// ---- stats helpers ---------------------------------------------------------
static __device__ __forceinline__ void stat_acc(const f32x4 acc[4], float sacc[4],
                                                float qacc[4]) {
#pragma unroll
  for (int t = 0; t < 4; t++) {
    sacc[t] += (acc[t][0] + acc[t][1]) + (acc[t][2] + acc[t][3]);
    qacc[t] = fmaf(acc[t][0], acc[t][0],
              fmaf(acc[t][1], acc[t][1],
              fmaf(acc[t][2], acc[t][2],
              fmaf(acc[t][3], acc[t][3], qacc[t]))));
  }
}

static __device__ __forceinline__ void stat_flush(float sacc[4], float qacc[4],
                                                  int quad, int n16, float* lstat) {
#pragma unroll
  for (int t = 0; t < 4; t++) {
    float s = sacc[t], q = qacc[t];
    s += __shfl_xor(s, 16); s += __shfl_xor(s, 32);
    q += __shfl_xor(q, 16); q += __shfl_xor(q, 32);
    if (quad == 0) {
      atomicAdd(&lstat[16 * t + n16], s);
      atomicAdd(&lstat[64 + 16 * t + n16], q);
    }
  }
}

// folded BN finalize: per-block recompute of bn coeffs from the 16-slot gacc
static __device__ __forceinline__ void bn_finalize(const float* __restrict__ gacc,
                                                   const float* __restrict__ g,
                                                   const float* __restrict__ be,
                                                   float* lbn, int tid) {
  if (tid < 64) {
    float s = 0.f, q = 0.f;
#pragma unroll
    for (int i = 0; i < GSLOTS; i++) {
      s += gacc[i * 128 + tid];
      q += gacc[i * 128 + 64 + tid];
    }
    float mean = s * (1.0f / E_EDGES);
    float var = q * (1.0f / E_EDGES) - mean * mean;  // biased, matches ref
    float rstd = rsqrtf(var + BN_EPS);
    float a = g[tid] * rstd;
    lbn[tid] = a;
    lbn[64 + tid] = be[tid] - mean * a;  // bn(v) = v*a + b
  }
}

// ---- pass 1': BN1 stats via gather of Z (NO MFMA) --------------------------
// h1_e[c] = Y[i][c] + Z[j][c]; accumulate sum/sumsq per channel.
// Lane (quad,n16): edge n16 of node p, channels quad*8+j and 32+quad*8+j.
// No min-waves bound: actual VGPR/LDS allow up to 8 blocks/CU.
__global__ __launch_bounds__(256) void k_stats1(const short* __restrict__ Z,
                                                const float* __restrict__ Yf,
                                                const int* __restrict__ ecol,
                                                float* __restrict__ gacc) {
  __shared__ float lstat[128];
  __shared__ float ytile[1024];   // 16 nodes x 64 ch (f32)
  int tid = threadIdx.x;
  if (tid < 128) lstat[tid] = 0.f;
  int nb = blockIdx.x * 16;
  ((float4*)ytile)[tid] = ((const float4*)(Yf + (size_t)nb * 64))[tid];
  int wave = tid >> 6, l = tid & 63, quad = l >> 4, n16 = l & 15;
  int idx[4];
#pragma unroll
  for (int v = 0; v < 4; v++)
    idx[v] = ecol[nb * KE + (wave * 4 + v) * 16 + n16];
  bf16x8 zf0[4], zf1[4];
#pragma unroll
  for (int v = 0; v < 4; v++) {
    const short* pz = Z + (size_t)idx[v] * 64 + quad * 8;
    zf0[v] = *(const bf16x8*)pz;
    zf1[v] = *(const bf16x8*)(pz + 32);
  }
  __syncthreads();
  float s0[8], q0[8], s1[8], q1[8];
#pragma unroll
  for (int j = 0; j < 8; j++) { s0[j] = q0[j] = s1[j] = q1[j] = 0.f; }
#pragma unroll
  for (int v = 0; v < 4; v++) {
    int p = wave * 4 + v;
    const float* yb = &ytile[p * 64 + quad * 8];
#pragma unroll
    for (int j = 0; j < 8; j++) {
      float h = yb[j] + bf2f(zf0[v][j]);
      s0[j] += h; q0[j] = fmaf(h, h, q0[j]);
      float h2 = yb[32 + j] + bf2f(zf1[v][j]);
      s1[j] += h2; q1[j] = fmaf(h2, h2, q1[j]);
    }
  }
  // reduce over the 16 edge-lanes (n16 bits 0..3)
#pragma unroll
  for (int j = 0; j < 8; j++) {
#pragma unroll
    for (int d = 1; d < 16; d <<= 1) {
      s0[j] += __shfl_xor(s0[j], d); q0[j] += __shfl_xor(q0[j], d);
      s1[j] += __shfl_xor(s1[j], d); q1[j] += __shfl_xor(q1[j], d);
    }
  }
  if (n16 == 0) {
#pragma unroll
    for (int j = 0; j < 8; j++) {
      atomicAdd(&lstat[quad * 8 + j], s0[j]);
      atomicAdd(&lstat[64 + quad * 8 + j], q0[j]);
      atomicAdd(&lstat[32 + quad * 8 + j], s1[j]);
      atomicAdd(&lstat[96 + quad * 8 + j], q1[j]);
    }
  }
  __syncthreads();
  if (tid < 128)
    atomicAdd(&gacc[(blockIdx.x & (GSLOTS - 1)) * 128 + tid], lstat[tid]);
}

// ---- pass 2': gather Z -> in-register BN1/ReLU -> GEMM2 + stats2 + minmax --
// A-frag built directly: lane l holds relu(a_c*Z[j][c] + B[i][c]) for
// edge m=l&15, channels c=(l>>4)*8+j — no LDS transpose tile, no GEMM1.
// No min-waves bound: actual VGPR/LDS allow up to 8 blocks/CU.
__global__ __launch_bounds__(256) void k_pass2(const short* __restrict__ Z,
                                               const float* __restrict__ Yf,
                                               const int* __restrict__ ecol,
                                               const bf16x8* __restrict__ wp2,
                                               const float* __restrict__ gacc1,
                                               const float* __restrict__ g1,
                                               const float* __restrict__ be1,
                                               float* __restrict__ gacc,
                                               short* __restrict__ hmax,
                                               short* __restrict__ hmin) {
  __shared__ float lstat[128];
  __shared__ float lbn[128];
  __shared__ float btile[1024];   // bias: a_c*Y[i][c] + b_c, 16 nodes x 64 ch
  int tid = threadIdx.x;
  if (tid < 128) lstat[tid] = 0.f;
  bn_finalize(gacc1, g1, be1, lbn, tid);
  int nb = blockIdx.x * 16;
  int wave = tid >> 6, l = tid & 63, quad = l >> 4, n16 = l & 15;
  int idx[4];
#pragma unroll
  for (int v = 0; v < 4; v++)
    idx[v] = ecol[nb * KE + (wave * 4 + v) * 16 + n16];
  bf16x8 zf0[4], zf1[4];
#pragma unroll
  for (int v = 0; v < 4; v++) {
    const short* pz = Z + (size_t)idx[v] * 64 + quad * 8;
    zf0[v] = *(const bf16x8*)pz;
    zf1[v] = *(const bf16x8*)(pz + 32);
  }
  bf16x8 wf2[8];
#pragma unroll
  for (int u = 0; u < 8; u++) wf2[u] = wp2[u * 64 + l];
  __syncthreads();                       // lbn ready
  for (int i = tid; i < 1024; i += 256)  // bias tile (Y reads coalesced)
    btile[i] = fmaf(lbn[i & 63], Yf[(size_t)nb * 64 + i], lbn[64 + (i & 63)]);
  __syncthreads();                       // btile ready
  float ac0[8], ac1[8];
#pragma unroll
  for (int j = 0; j < 8; j++) {
    ac0[j] = lbn[quad * 8 + j];
    ac1[j] = lbn[32 + quad * 8 + j];
  }
  float sacc[4] = {0.f, 0.f, 0.f, 0.f}, qacc[4] = {0.f, 0.f, 0.f, 0.f};
#pragma unroll
  for (int v = 0; v < 4; v++) {
    int p = wave * 4 + v;
    const float* bb = &btile[p * 64 + quad * 8];
    float h0[8], h1[8];
#pragma unroll
    for (int j = 0; j < 8; j++) {
      h0[j] = fmaxf(fmaf(ac0[j], bf2f(zf0[v][j]), bb[j]), 0.f);
      h1[j] = fmaxf(fmaf(ac1[j], bf2f(zf1[v][j]), bb[32 + j]), 0.f);
    }
    bf16x8 f0 = pack8f(h0), f1 = pack8f(h1);
    f32x4 acc2[4];
#pragma unroll
    for (int t = 0; t < 4; t++) {
      f32x4 a = {0.f, 0.f, 0.f, 0.f};
      a = MFMA(f0, wf2[0 + t], a);
      a = MFMA(f1, wf2[4 + t], a);
      acc2[t] = a;
    }
    stat_acc(acc2, sacc, qacc);
    // per-node, per-channel max & min of h2_pre over the 16 edges
    float vmx[4], vmn[4];
#pragma unroll
    for (int t = 0; t < 4; t++) {
      float mx = fmaxf(fmaxf(acc2[t][0], acc2[t][1]), fmaxf(acc2[t][2], acc2[t][3]));
      float mn = fminf(fminf(acc2[t][0], acc2[t][1]), fminf(acc2[t][2], acc2[t][3]));
      mx = fmaxf(mx, __shfl_xor(mx, 16)); mx = fmaxf(mx, __shfl_xor(mx, 32));
      mn = fminf(mn, __shfl_xor(mn, 16)); mn = fminf(mn, __shfl_xor(mn, 32));
      vmx[t] = mx; vmn[t] = mn;
    }
    int n = nb + p;
    float ox = (quad == 0) ? vmx[0] : (quad == 1) ? vmx[1] : (quad == 2) ? vmx[2] : vmx[3];
    float on = (quad == 0) ? vmn[0] : (quad == 1) ? vmn[1] : (quad == 2) ? vmn[2] : vmn[3];
    hmax[(size_t)n * 64 + l] = bf16b(ox);  // lane l == channel l: coalesced
    hmin[(size_t)n * 64 + l] = bf16b(on);
  }
  stat_flush(sacc, qacc, quad, n16, lstat);
  __syncthreads();
  if (tid < 128)
    atomicAdd(&gacc[(blockIdx.x & (GSLOTS - 1)) * 128 + tid], lstat[tid]);
}

// ---- pass 3: folded finalize2 + elementwise BN2/ReLU + min/max select ------
// max_m relu(a*h+b) = relu(a>=0 ? a*hmax+b : a*hmin+b)  (affine+relu monotone)
__global__ __launch_bounds__(256) void k_pass3(const short* __restrict__ hmax,
                                               const short* __restrict__ hmin,
                                               const float* __restrict__ gacc2,
                                               const float* __restrict__ g2,
                                               const float* __restrict__ be2,
                                               float* __restrict__ out) {
  __shared__ float lbn[128];
  int tid = threadIdx.x;
  bn_finalize(gacc2, g2, be2, lbn, tid);  // folded finalize2
  __syncthreads();
  int g = blockIdx.x * 256 + tid;  // 1.6M threads, 4 channels each
  int base = g * 4;
  int c4 = base & 63;
  short4 mx4 = *(const short4*)(hmax + base);
  short4 mn4 = *(const short4*)(hmin + base);
  float4 a4 = *(const float4*)(&lbn[c4]);
  float4 b4 = *(const float4*)(&lbn[64 + c4]);
  float4 o;
  o.x = fmaxf(a4.x >= 0.f ? fmaf(a4.x, bf2f(mx4.x), b4.x) : fmaf(a4.x, bf2f(mn4.x), b4.x), 0.f);
  o.y = fmaxf(a4.y >= 0.f ? fmaf(a4.y, bf2f(mx4.y), b4.y) : fmaf(a4.y, bf2f(mn4.y), b4.y), 0.f);
  o.z = fmaxf(a4.z >= 0.f ? fmaf(a4.z, bf2f(mx4.z), b4.z) : fmaf(a4.z, bf2f(mn4.z), b4.z), 0.f);
  o.w = fmaxf(a4.w >= 0.f ? fmaf(a4.w, bf2f(mx4.w), b4.w) : fmaf(a4.w, bf2f(mn4.w), b4.w), 0.f);
  *(float4*)(out + base) = o;
}

extern "C" void kernel_launch(void* const* d_in, const int* in_sizes, int n_in,
                              void* d_out, int out_size, void* d_ws, size_t ws_size,
                              hipStream_t stream) {
  const float* x   = (const float*)d_in[0];
  // d_in[1] = edge_row: structurally repeat(arange(N),16), unused
  const int*   ec  = (const int*)d_in[2];
  const float* W1  = (const float*)d_in[3];
  // d_in[4] = b1: cancels in BN, unused
  const float* g1  = (const float*)d_in[5];
  const float* be1 = (const float*)d_in[6];
  const float* W2  = (const float*)d_in[7];
  // d_in[8] = b2: cancels in BN, unused
  const float* g2  = (const float*)d_in[9];
  const float* be2 = (const float*)d_in[10];
  float* out = (float*)d_out;

  char* ws = (char*)d_ws;
  bf16x8* wp1  = (bf16x8*)(ws);                 // 16 KB packed W1 (split)
  bf16x8* wp2  = (bf16x8*)(ws + 16384);         // 8 KB packed W2
  float* gacc1 = (float*)(ws + 24576);          // 16 slots x 128 = 8 KB
  float* gacc2 = (float*)(ws + 32768);          // 8 KB
  float* Yf    = (float*)(ws + 98304);          // Y = X@Wd f32: 25.6 MB
  short* Zb    = (short*)(ws + 98304 + 25600000);          // Z bf16: 12.8 MB
  short* hmax  = (short*)(ws + 98304 + 25600000 + 12800000);       // 12.8 MB
  short* hmin  = (short*)(ws + 98304 + 25600000 + 2 * 12800000);   // 12.8 MB

  hipLaunchKernelGGL(k_prep, dim3(7), dim3(256), 0, stream,
                     W1, W2, (short*)wp1, (short*)wp2, gacc1);
  hipLaunchKernelGGL(k_nodeYZ, dim3((NTILES + 3) / 4), dim3(256), 0, stream,
                     x, wp1, Yf, Zb);
  hipLaunchKernelGGL(k_stats1, dim3(NCHUNK), dim3(256), 0, stream,
                     Zb, Yf, ec, gacc1);
  hipLaunchKernelGGL(k_pass2, dim3(NCHUNK), dim3(256), 0, stream,
                     Zb, Yf, ec, wp2, gacc1, g1, be1, gacc2, hmax, hmin);
  hipLaunchKernelGGL(k_pass3, dim3(6250), dim3(256), 0, stream,
                     hmax, hmin, gacc2, g2, be2, out);
}

// Round 5
// 216.220 us; speedup vs baseline: 1.1498x; 1.1498x over previous
//
#include <hip/hip_runtime.h>

// EdgeConv fused pipeline, MI355X gfx950 — round 13.
// R12 post-mortem: unbounded launch -> VGPR drifted 64->76, crossing the
// 64-reg occupancy boundary (waves/SIMD halve at vgpr={64,128}) -> occupancy
// 38->29%, pass2 70->78us. (256,4) is the sweet spot: tighter caps spill
// (R7/R9), looser drifts past 64 (R12).
// Ledger subtraction: scalar k_stats1 ~= 105us > R10's MFMA pass1 (~82us).
// Cause: 64 scalar ops/v/lane + a 128-shfl tree to reduce over edge-lanes.
// R13: MFMA-TRANSPOSE stats1 — multiply gathered Z A-frags by constant
// identity B-frags (e0=delta(k,n), e1=delta(k,16+n), exact in bf16):
// D = Z*E lands Z channel-major (lane=channel, rows=edges), so the edge
// reduction becomes 3 adds + 2 shfls per t (R10's stat_flush). Kills all
// bf2f unpacking and the shuffle tree; reduction rides the idle MFMA pipe.
// pass2 reverted byte-exact to R11's 70us version.

#define N_NODES 100000
#define KE 16
#define E_EDGES (N_NODES * KE)
#define BN_EPS 1e-5f
#define NCHUNK (N_NODES / KE)      // 6250 16-node block-chunks (exact)
#define NTILES (N_NODES / 16)      // 6250 16-node GEMM tiles (exact)
#define GSLOTS 16

typedef __attribute__((ext_vector_type(8))) short bf16x8;  // 8 bf16 (4 VGPRs)
typedef __attribute__((ext_vector_type(4))) float f32x4;   // MFMA C/D
typedef __attribute__((ext_vector_type(4))) int i32x4;

#define MFMA(a, b, c) __builtin_amdgcn_mfma_f32_16x16x32_bf16((a), (b), (c), 0, 0, 0)

static __device__ __forceinline__ short bf16b(float f) {
  __bf16 h = (__bf16)f;  // RNE, hardware cvt on gfx950
  return __builtin_bit_cast(short, h);
}

#if __has_builtin(__builtin_amdgcn_cvt_pk_bf16_f32)
static __device__ __forceinline__ int pk2(float a, float b) {
  return __builtin_bit_cast(int, __builtin_amdgcn_cvt_pk_bf16_f32(a, b));
}
#else
static __device__ __forceinline__ int pk2(float a, float b) {
  return (int)(unsigned short)bf16b(a) | ((int)(unsigned short)bf16b(b) << 16);
}
#endif

static __device__ __forceinline__ bf16x8 pack8(float4 a, float4 b) {
  i32x4 v = {pk2(a.x, a.y), pk2(a.z, a.w), pk2(b.x, b.y), pk2(b.z, b.w)};
  return __builtin_bit_cast(bf16x8, v);
}

static __device__ __forceinline__ bf16x8 pack8f(const float h[8]) {
  i32x4 v = {pk2(h[0], h[1]), pk2(h[2], h[3]), pk2(h[4], h[5]), pk2(h[6], h[7])};
  return __builtin_bit_cast(bf16x8, v);
}

static __device__ __forceinline__ float bf2f(short s) {
  unsigned u = ((unsigned)(unsigned short)s) << 16;
  return __builtin_bit_cast(float, u);
}

// ---- prep: weight packing + gacc zeroing -----------------------------------
// wp1[(s*4+t)*64 + l] holds 8 bf16: B[k=32s + (l>>4)*8 + j][c=16t + (l&15)]
// s=0,1 -> Wd = W1[:64]-W1[64:] (xi part); s=2,3 -> Wb = W1[64:] (xj part).
__global__ __launch_bounds__(256) void k_prep(const float* __restrict__ W1,
                                              const float* __restrict__ W2,
                                              short* __restrict__ wp1,
                                              short* __restrict__ wp2,
                                              float* __restrict__ gaccz) {
  if (blockIdx.x == 6) {  // zero both gacc buffers (4096 floats)
    float4 z = {0.f, 0.f, 0.f, 0.f};
    for (int i = 0; i < 4; i++)
      ((float4*)gaccz)[threadIdx.x * 4 + i] = z;
    return;
  }
  int tid = blockIdx.x * 256 + threadIdx.x;
  if (tid < 1024) {
    int l = tid & 63, st = tid >> 6;
    int s = st >> 2, t = st & 3;
    int quad = l >> 4, n16 = l & 15;
    for (int j = 0; j < 8; j++) {
      int k = 32 * s + quad * 8 + j, c = 16 * t + n16;
      float w = (s < 2) ? (W1[k * 64 + c] - W1[(k + 64) * 64 + c])
                        : W1[k * 64 + c];
      wp1[tid * 8 + j] = bf16b(w);
    }
  } else if (tid < 1536) {
    int e = tid - 1024;
    int l = e & 63, st = e >> 6;
    int s = st >> 2, t = st & 3;
    int quad = l >> 4, n16 = l & 15;
    for (int j = 0; j < 8; j++) {
      int k = 32 * s + quad * 8 + j, c = 16 * t + n16;
      wp2[e * 8 + j] = bf16b(W2[k * 64 + c]);
    }
  }
}

// ---- node GEMMs: Y = X@Wd (f32), Z = X@Wb (bf16) ---------------------------
// One 16-node tile per wave; A-frags packed on the fly from f32 x.
__global__ __launch_bounds__(256) void k_nodeYZ(const float* __restrict__ x,
                                                const bf16x8* __restrict__ wp1,
                                                float* __restrict__ Yf,
                                                short* __restrict__ Z) {
  int wave = threadIdx.x >> 6, l = threadIdx.x & 63, quad = l >> 4, n16 = l & 15;
  int tile = blockIdx.x * 4 + wave;
  if (tile >= NTILES) return;
  const float* xr = x + (size_t)(tile * 16 + n16) * 64 + quad * 8;
  float4 x0 = *(const float4*)xr, x1 = *(const float4*)(xr + 4);
  float4 x2 = *(const float4*)(xr + 32), x3 = *(const float4*)(xr + 36);
  bf16x8 a0 = pack8(x0, x1);   // A[m=n16][k = quad*8+j]       (ch 0..31)
  bf16x8 a1 = pack8(x2, x3);   // A[m=n16][k = 32+quad*8+j]    (ch 32..63)
  f32x4 zero = {0.f, 0.f, 0.f, 0.f};
#pragma unroll
  for (int t = 0; t < 4; t++) {
    f32x4 y = MFMA(a0, wp1[(0 + t) * 64 + l], zero);
    y = MFMA(a1, wp1[(4 + t) * 64 + l], y);
    f32x4 z = MFMA(a0, wp1[(8 + t) * 64 + l], zero);
    z = MFMA(a1, wp1[(12 + t) * 64 + l], z);
#pragma unroll
    for (int r = 0; r < 4; r++) {  // D: row = quad*4+r, col = 16t+n16
      size_t row = (size_t)(tile * 16 + quad * 4 + r);
      Yf[row * 64 + 16 * t + n16] = y[r];
      Z[row * 64 + 16 * t + n16] = bf16b(z[r]);
    }
  }
}

// ---- stats helpers ---------------------------------------------------------
static __device__ __forceinline__ void stat_acc(const f32x4 acc[4], float sacc[4],
                                                float qacc[4]) {
#pragma unroll
  for (int t = 0; t < 4; t++) {
    sacc[t] += (acc[t][0] + acc[t][1]) + (acc[t][2] + acc[t][3]);
    qacc[t] = fmaf(acc[t][0], acc[t][0],
              fmaf(acc[t][1], acc[t][1],
              fmaf(acc[t][2], acc[t][2],
              fmaf(acc[t][3], acc[t][3], qacc[t]))));
  }
}

static __device__ __forceinline__ void stat_flush(float sacc[4], float qacc[4],
                                                  int quad, int n16, float* lstat) {
#pragma unroll
  for (int t = 0; t < 4; t++) {
    float s = sacc[t], q = qacc[t];
    s += __shfl_xor(s, 16); s += __shfl_xor(s, 32);
    q += __shfl_xor(q, 16); q += __shfl_xor(q, 32);
    if (quad == 0) {
      atomicAdd(&lstat[16 * t + n16], s);
      atomicAdd(&lstat[64 + 16 * t + n16], q);
    }
  }
}

// folded BN finalize: per-block recompute of bn coeffs from the 16-slot gacc
static __device__ __forceinline__ void bn_finalize(const float* __restrict__ gacc,
                                                   const float* __restrict__ g,
                                                   const float* __restrict__ be,
                                                   float* lbn, int tid) {
  if (tid < 64) {
    float s = 0.f, q = 0.f;
#pragma unroll
    for (int i = 0; i < GSLOTS; i++) {
      s += gacc[i * 128 + tid];
      q += gacc[i * 128 + 64 + tid];
    }
    float mean = s * (1.0f / E_EDGES);
    float var = q * (1.0f / E_EDGES) - mean * mean;  // biased, matches ref
    float rstd = rsqrtf(var + BN_EPS);
    float a = g[tid] * rstd;
    lbn[tid] = a;
    lbn[64 + tid] = be[tid] - mean * a;  // bn(v) = v*a + b
  }
}

// ---- pass 1': BN1 stats via gather of Z + MFMA identity-transpose ----------
// D = Z_frags x E (E = identity B-frag, exact in bf16) re-lands Z
// channel-major: lane(quad,n16) reg r -> edge quad*4+r, channel 16t+n16.
// h = D[r] + Y[p][c]; edge-reduce = 3 adds + 2 shfls per t (stat_flush).
__global__ __launch_bounds__(256, 4) void k_stats1(const short* __restrict__ Z,
                                                   const float* __restrict__ Yf,
                                                   const int* __restrict__ ecol,
                                                   float* __restrict__ gacc) {
  __shared__ float lstat[128];
  __shared__ float ytile[1024];   // 16 nodes x 64 ch (f32)
  int tid = threadIdx.x;
  if (tid < 128) lstat[tid] = 0.f;
  int nb = blockIdx.x * 16;
  ((float4*)ytile)[tid] = ((const float4*)(Yf + (size_t)nb * 64))[tid];
  int wave = tid >> 6, l = tid & 63, quad = l >> 4, n16 = l & 15;
  int idx[4];
#pragma unroll
  for (int v = 0; v < 4; v++)
    idx[v] = ecol[nb * KE + (wave * 4 + v) * 16 + n16];
  bf16x8 zf0[4], zf1[4];
#pragma unroll
  for (int v = 0; v < 4; v++) {
    const short* pz = Z + (size_t)idx[v] * 64 + quad * 8;
    zf0[v] = *(const bf16x8*)pz;
    zf1[v] = *(const bf16x8*)(pz + 32);
  }
  // identity B-frags: e0[k][n] = (k==n), e1[k][n] = (k==16+n); k = quad*8+j
  short one = bf16b(1.0f);
  bf16x8 e0, e1;
#pragma unroll
  for (int j = 0; j < 8; j++) {
    e0[j] = (quad * 8 + j == n16) ? one : (short)0;
    e1[j] = (quad * 8 + j == n16 + 16) ? one : (short)0;
  }
  __syncthreads();
  f32x4 zero = {0.f, 0.f, 0.f, 0.f};
  float sacc[4] = {0.f, 0.f, 0.f, 0.f}, qacc[4] = {0.f, 0.f, 0.f, 0.f};
#pragma unroll
  for (int v = 0; v < 4; v++) {
    int p = wave * 4 + v;
    f32x4 d[4];
    d[0] = MFMA(zf0[v], e0, zero);   // channels  0..15
    d[1] = MFMA(zf0[v], e1, zero);   // channels 16..31
    d[2] = MFMA(zf1[v], e0, zero);   // channels 32..47
    d[3] = MFMA(zf1[v], e1, zero);   // channels 48..63
#pragma unroll
    for (int t = 0; t < 4; t++) {
      float yv = ytile[p * 64 + 16 * t + n16];
#pragma unroll
      for (int r = 0; r < 4; r++) {
        float h = d[t][r] + yv;
        sacc[t] += h;
        qacc[t] = fmaf(h, h, qacc[t]);
      }
    }
  }
  stat_flush(sacc, qacc, quad, n16, lstat);
  __syncthreads();
  if (tid < 128)
    atomicAdd(&gacc[(blockIdx.x & (GSLOTS - 1)) * 128 + tid], lstat[tid]);
}

// ---- pass 2': gather Z -> in-register BN1/ReLU -> GEMM2 + stats2 + minmax --
// A-frag built directly: lane l holds relu(a_c*Z[j][c] + B[i][c]) for
// edge m=l&15, channels c=(l>>4)*8+j — no LDS transpose tile, no GEMM1.
// (256,4): cap 128, natural VGPR 64 -> proven 70us config (R11).
__global__ __launch_bounds__(256, 4) void k_pass2(const short* __restrict__ Z,
                                                  const float* __restrict__ Yf,
                                                  const int* __restrict__ ecol,
                                                  const bf16x8* __restrict__ wp2,
                                                  const float* __restrict__ gacc1,
                                                  const float* __restrict__ g1,
                                                  const float* __restrict__ be1,
                                                  float* __restrict__ gacc,
                                                  short* __restrict__ hmax,
                                                  short* __restrict__ hmin) {
  __shared__ float lstat[128];
  __shared__ float lbn[128];
  __shared__ float btile[1024];   // bias: a_c*Y[i][c] + b_c, 16 nodes x 64 ch
  int tid = threadIdx.x;
  if (tid < 128) lstat[tid] = 0.f;
  bn_finalize(gacc1, g1, be1, lbn, tid);
  int nb = blockIdx.x * 16;
  int wave = tid >> 6, l = tid & 63, quad = l >> 4, n16 = l & 15;
  int idx[4];
#pragma unroll
  for (int v = 0; v < 4; v++)
    idx[v] = ecol[nb * KE + (wave * 4 + v) * 16 + n16];
  bf16x8 zf0[4], zf1[4];
#pragma unroll
  for (int v = 0; v < 4; v++) {
    const short* pz = Z + (size_t)idx[v] * 64 + quad * 8;
    zf0[v] = *(const bf16x8*)pz;
    zf1[v] = *(const bf16x8*)(pz + 32);
  }
  bf16x8 wf2[8];
#pragma unroll
  for (int u = 0; u < 8; u++) wf2[u] = wp2[u * 64 + l];
  __syncthreads();                       // lbn ready
  for (int i = tid; i < 1024; i += 256)  // bias tile (Y reads coalesced)
    btile[i] = fmaf(lbn[i & 63], Yf[(size_t)nb * 64 + i], lbn[64 + (i & 63)]);
  __syncthreads();                       // btile ready
  float ac0[8], ac1[8];
#pragma unroll
  for (int j = 0; j < 8; j++) {
    ac0[j] = lbn[quad * 8 + j];
    ac1[j] = lbn[32 + quad * 8 + j];
  }
  float sacc[4] = {0.f, 0.f, 0.f, 0.f}, qacc[4] = {0.f, 0.f, 0.f, 0.f};
#pragma unroll
  for (int v = 0; v < 4; v++) {
    int p = wave * 4 + v;
    const float* bb = &btile[p * 64 + quad * 8];
    float h0[8], h1[8];
#pragma unroll
    for (int j = 0; j < 8; j++) {
      h0[j] = fmaxf(fmaf(ac0[j], bf2f(zf0[v][j]), bb[j]), 0.f);
      h1[j] = fmaxf(fmaf(ac1[j], bf2f(zf1[v][j]), bb[32 + j]), 0.f);
    }
    bf16x8 f0 = pack8f(h0), f1 = pack8f(h1);
    f32x4 acc2[4];
#pragma unroll
    for (int t = 0; t < 4; t++) {
      f32x4 a = {0.f, 0.f, 0.f, 0.f};
      a = MFMA(f0, wf2[0 + t], a);
      a = MFMA(f1, wf2[4 + t], a);
      acc2[t] = a;
    }
    stat_acc(acc2, sacc, qacc);
    // per-node, per-channel max & min of h2_pre over the 16 edges
    float vmx[4], vmn[4];
#pragma unroll
    for (int t = 0; t < 4; t++) {
      float mx = fmaxf(fmaxf(acc2[t][0], acc2[t][1]), fmaxf(acc2[t][2], acc2[t][3]));
      float mn = fminf(fminf(acc2[t][0], acc2[t][1]), fminf(acc2[t][2], acc2[t][3]));
      mx = fmaxf(mx, __shfl_xor(mx, 16)); mx = fmaxf(mx, __shfl_xor(mx, 32));
      mn = fminf(mn, __shfl_xor(mn, 16)); mn = fminf(mn, __shfl_xor(mn, 32));
      vmx[t] = mx; vmn[t] = mn;
    }
    int n = nb + p;
    float ox = (quad == 0) ? vmx[0] : (quad == 1) ? vmx[1] : (quad == 2) ? vmx[2] : vmx[3];
    float on = (quad == 0) ? vmn[0] : (quad == 1) ? vmn[1] : (quad == 2) ? vmn[2] : vmn[3];
    hmax[(size_t)n * 64 + l] = bf16b(ox);  // lane l == channel l: coalesced
    hmin[(size_t)n * 64 + l] = bf16b(on);
  }
  stat_flush(sacc, qacc, quad, n16, lstat);
  __syncthreads();
  if (tid < 128)
    atomicAdd(&gacc[(blockIdx.x & (GSLOTS - 1)) * 128 + tid], lstat[tid]);
}

// ---- pass 3: folded finalize2 + elementwise BN2/ReLU + min/max select ------
// max_m relu(a*h+b) = relu(a>=0 ? a*hmax+b : a*hmin+b)  (affine+relu monotone)
__global__ __launch_bounds__(256) void k_pass3(const short* __restrict__ hmax,
                                               const short* __restrict__ hmin,
                                               const float* __restrict__ gacc2,
                                               const float* __restrict__ g2,
                                               const float* __restrict__ be2,
                                               float* __restrict__ out) {
  __shared__ float lbn[128];
  int tid = threadIdx.x;
  bn_finalize(gacc2, g2, be2, lbn, tid);  // folded finalize2
  __syncthreads();
  int g = blockIdx.x * 256 + tid;  // 1.6M threads, 4 channels each
  int base = g * 4;
  int c4 = base & 63;
  short4 mx4 = *(const short4*)(hmax + base);
  short4 mn4 = *(const short4*)(hmin + base);
  float4 a4 = *(const float4*)(&lbn[c4]);
  float4 b4 = *(const float4*)(&lbn[64 + c4]);
  float4 o;
  o.x = fmaxf(a4.x >= 0.f ? fmaf(a4.x, bf2f(mx4.x), b4.x) : fmaf(a4.x, bf2f(mn4.x), b4.x), 0.f);
  o.y = fmaxf(a4.y >= 0.f ? fmaf(a4.y, bf2f(mx4.y), b4.y) : fmaf(a4.y, bf2f(mn4.y), b4.y), 0.f);
  o.z = fmaxf(a4.z >= 0.f ? fmaf(a4.z, bf2f(mx4.z), b4.z) : fmaf(a4.z, bf2f(mn4.z), b4.z), 0.f);
  o.w = fmaxf(a4.w >= 0.f ? fmaf(a4.w, bf2f(mx4.w), b4.w) : fmaf(a4.w, bf2f(mn4.w), b4.w), 0.f);
  *(float4*)(out + base) = o;
}

extern "C" void kernel_launch(void* const* d_in, const int* in_sizes, int n_in,
                              void* d_out, int out_size, void* d_ws, size_t ws_size,
                              hipStream_t stream) {
  const float* x   = (const float*)d_in[0];
  // d_in[1] = edge_row: structurally repeat(arange(N),16), unused
  const int*   ec  = (const int*)d_in[2];
  const float* W1  = (const float*)d_in[3];
  // d_in[4] = b1: cancels in BN, unused
  const float* g1  = (const float*)d_in[5];
  const float* be1 = (const float*)d_in[6];
  const float* W2  = (const float*)d_in[7];
  // d_in[8] = b2: cancels in BN, unused
  const float* g2  = (const float*)d_in[9];
  const float* be2 = (const float*)d_in[10];
  float* out = (float*)d_out;

  char* ws = (char*)d_ws;
  bf16x8* wp1  = (bf16x8*)(ws);                 // 16 KB packed W1 (split)
  bf16x8* wp2  = (bf16x8*)(ws + 16384);         // 8 KB packed W2
  float* gacc1 = (float*)(ws + 24576);          // 16 slots x 128 = 8 KB
  float* gacc2 = (float*)(ws + 32768);          // 8 KB
  float* Yf    = (float*)(ws + 98304);          // Y = X@Wd f32: 25.6 MB
  short* Zb    = (short*)(ws + 98304 + 25600000);          // Z bf16: 12.8 MB
  short* hmax  = (short*)(ws + 98304 + 25600000 + 12800000);       // 12.8 MB
  short* hmin  = (short*)(ws + 98304 + 25600000 + 2 * 12800000);   // 12.8 MB

  hipLaunchKernelGGL(k_prep, dim3(7), dim3(256), 0, stream,
                     W1, W2, (short*)wp1, (short*)wp2, gacc1);
  hipLaunchKernelGGL(k_nodeYZ, dim3((NTILES + 3) / 4), dim3(256), 0, stream,
                     x, wp1, Yf, Zb);
  hipLaunchKernelGGL(k_stats1, dim3(NCHUNK), dim3(256), 0, stream,
                     Zb, Yf, ec, gacc1);
  hipLaunchKernelGGL(k_pass2, dim3(NCHUNK), dim3(256), 0, stream,
                     Zb, Yf, ec, wp2, gacc1, g1, be1, gacc2, hmax, hmin);
  hipLaunchKernelGGL(k_pass3, dim3(6250), dim3(256), 0, stream,
                     hmax, hmin, gacc2, g2, be2, out);
}